// Round 1
// baseline (420.047 us; speedup 1.0000x reference)
//
#include <hip/hip_runtime.h>
#include <stdint.h>

#define SLEN 4096
#define NROWS 8192          // 128 * 64
#define VIEW_ELEMS 33554432 // 128 * 64 * 4096

// ---------------- threefry2x32 (JAX-exact, 20 rounds) ----------------
__device__ __forceinline__ uint32_t rotl32(uint32_t x, uint32_t r) {
  return (x << r) | (x >> (32u - r));
}

__device__ __forceinline__ void tf2x32(uint32_t k0, uint32_t k1,
                                       uint32_t x0, uint32_t x1,
                                       uint32_t* o0, uint32_t* o1) {
  uint32_t ks2 = k0 ^ k1 ^ 0x1BD11BDAu;
  x0 += k0; x1 += k1;
#define TFR(r) { x0 += x1; x1 = rotl32(x1, r); x1 ^= x0; }
  TFR(13) TFR(15) TFR(26) TFR(6)
  x0 += k1; x1 += ks2 + 1u;
  TFR(17) TFR(29) TFR(16) TFR(24)
  x0 += ks2; x1 += k0 + 2u;
  TFR(13) TFR(15) TFR(26) TFR(6)
  x0 += k0; x1 += k1 + 3u;
  TFR(17) TFR(29) TFR(16) TFR(24)
  x0 += k1; x1 += ks2 + 4u;
  TFR(13) TFR(15) TFR(26) TFR(6)
#undef TFR
  *o0 = x0 + ks2;
  *o1 = x1 + k0 + 5u;
}

// partitionable random_bits, 32-bit: xor of the two output words
__device__ __forceinline__ uint32_t tf_xor(uint32_t k0, uint32_t k1,
                                           uint32_t x0, uint32_t x1) {
  uint32_t a, b;
  tf2x32(k0, k1, x0, x1, &a, &b);
  return a ^ b;
}

// uniform [0,1): top 23 bits as mantissa of [1,2) minus 1  (bit-exact vs JAX)
__device__ __forceinline__ float unit_f(uint32_t bits) {
  return __uint_as_float((bits >> 9) | 0x3F800000u) - 1.0f;
}

// XLA ErfInv32 (Giles) — same coefficients as the CPU/GPU lowering of lax.erf_inv
__device__ __forceinline__ float erfinv_f(float x) {
  float w = -__logf(fmaf(x, -x, 1.0f));   // ~ -log1p(-x*x)
  float p;
  if (w < 5.0f) {
    w -= 2.5f;
    p = 2.81022636e-08f;
    p = fmaf(p, w, 3.43273939e-07f);
    p = fmaf(p, w, -3.5233877e-06f);
    p = fmaf(p, w, -4.39150654e-06f);
    p = fmaf(p, w, 0.00021858087f);
    p = fmaf(p, w, -0.00125372503f);
    p = fmaf(p, w, -0.00417768164f);
    p = fmaf(p, w, 0.246640727f);
    p = fmaf(p, w, 1.50140941f);
  } else {
    w = __fsqrt_rn(w) - 3.0f;
    p = -0.000200214257f;
    p = fmaf(p, w, 0.000100950558f);
    p = fmaf(p, w, 0.00134934322f);
    p = fmaf(p, w, -0.00367342844f);
    p = fmaf(p, w, 0.00573950773f);
    p = fmaf(p, w, -0.0076224613f);
    p = fmaf(p, w, 0.00943887047f);
    p = fmaf(p, w, 1.00167406f);
    p = fmaf(p, w, 2.83297682f);
  }
  return p * x;
}

// ---------------- params kernel: shifts, channel mask, scale, noise keys ----
// ws layout (4-byte units): [0,256) shifts[2][128] (int)
//                           [256,512) scale[2][128]
//                           [512,16896) mask[2][8192]
//                           [16896,16900) nkey[2][2] (uint32)
__global__ __launch_bounds__(256) void k_params(int* __restrict__ shifts,
                                                float* __restrict__ scalev,
                                                float* __restrict__ maskv,
                                                uint32_t* __restrict__ nkey) {
  int v = blockIdx.x;            // 0/1 -> fold_in data v+1
  int t = threadIdx.x;

  // key_v = fold_in(key(42), v+1) = threefry((0,42), (0, v+1))
  uint32_t kv0, kv1;
  tf2x32(0u, 42u, 0u, (uint32_t)(v + 1), &kv0, &kv1);

  // split(key_v, 4) fold-like: subkey_i = threefry(key_v, (0, i))
  uint32_t ks0, ks1, kn0, kn1, km0, km1, kc0, kc1;
  tf2x32(kv0, kv1, 0u, 0u, &ks0, &ks1);   // k_shift
  tf2x32(kv0, kv1, 0u, 1u, &kn0, &kn1);   // k_noise
  tf2x32(kv0, kv1, 0u, 2u, &km0, &km1);   // k_mask
  tf2x32(kv0, kv1, 0u, 3u, &kc0, &kc1);   // k_scale

  // randint's internal split of k_shift
  uint32_t h10, h11, h20, h21;
  tf2x32(ks0, ks1, 0u, 0u, &h10, &h11);   // k1 -> higher bits
  tf2x32(ks0, ks1, 0u, 1u, &h20, &h21);   // k2 -> lower bits

  if (t < 128) {
    // shift: span=101, multiplier=(2^16%101)^2%101 = 68
    uint32_t hb = tf_xor(h10, h11, 0u, (uint32_t)t);
    uint32_t lb = tf_xor(h20, h21, 0u, (uint32_t)t);
    uint32_t off = ((hb % 101u) * 68u + (lb % 101u)) % 101u;
    shifts[v * 128 + t] = -50 + (int)off;
    // per-sample amplitude scale: max(0.8, f*(1.2-0.8)+0.8)
    uint32_t sb = tf_xor(kc0, kc1, 0u, (uint32_t)t);
    scalev[v * 128 + t] = fmaxf(0.8f, unit_f(sb) * (1.2f - 0.8f) + 0.8f);
  }
  // channel dropout mask, 8192 values per view
  for (int j = t; j < 8192; j += 256) {
    uint32_t mb = tf_xor(km0, km1, 0u, (uint32_t)j);
    maskv[v * 8192 + j] = (unit_f(mb) > 0.1f) ? 1.0f : 0.0f;
  }
  if (t == 0) { nkey[v * 2] = kn0; nkey[v * 2 + 1] = kn1; }
}

// ---------------- main kernel: one (view,b,c) row of 4096 per block --------
__global__ __launch_bounds__(256) void k_main(const float* __restrict__ x,
                                              float* __restrict__ out,
                                              const int* __restrict__ shifts,
                                              const float* __restrict__ scalev,
                                              const float* __restrict__ maskv,
                                              const uint32_t* __restrict__ nkey) {
  __shared__ float red2[8];
  int blk = blockIdx.x;          // 16384 blocks = 2 views * 8192 rows
  int v = blk >> 13;
  int row = blk & 8191;          // b*64 + c
  int b = row >> 6;
  int t = threadIdx.x;

  int sh = shifts[v * 128 + b];
  float msc = maskv[v * 8192 + row] * scalev[v * 128 + b];  // exact: mask in {0,1}
  uint32_t nk0 = nkey[v * 2], nk1 = nkey[v * 2 + 1];

  const float* __restrict__ xr = x + (size_t)row * SLEN;

  // pass 1: rolled loads (a permutation of the row -> sums give row std)
  float vals[16];
  float sum = 0.0f, ss = 0.0f;
#pragma unroll
  for (int k = 0; k < 4; ++k) {
#pragma unroll
    for (int j = 0; j < 4; ++j) {
      int s = k * 1024 + t * 4 + j;
      int idx = (s - sh) & 4095;        // python-mod semantics via & on 2's-compl
      float a = xr[idx];
      vals[k * 4 + j] = a;
      sum += a;
      ss = fmaf(a, a, ss);
    }
  }
  // block reduction (sum, ss): wave butterfly then 4-partial LDS combine
#pragma unroll
  for (int o = 32; o > 0; o >>= 1) {
    sum += __shfl_xor(sum, o, 64);
    ss  += __shfl_xor(ss,  o, 64);
  }
  if ((t & 63) == 0) { red2[t >> 6] = sum; red2[4 + (t >> 6)] = ss; }
  __syncthreads();
  sum = red2[0] + red2[1] + red2[2] + red2[3];
  ss  = red2[4] + red2[5] + red2[6] + red2[7];
  float mean = sum * (1.0f / 4096.0f);
  float var = (ss - sum * mean) * (1.0f / 4095.0f);   // ddof=1
  float nscale = 0.1f * __fsqrt_rn(fmaxf(var, 0.0f)); // NOISE_STD * std

  // pass 2: noise bits (partitionable: one threefry per element), combine, store
  float* orow = out + (size_t)v * VIEW_ELEMS + (size_t)row * SLEN;
  uint32_t nbase = (uint32_t)row * 4096u;
#pragma unroll
  for (int k = 0; k < 4; ++k) {
    float tmp[4];
#pragma unroll
    for (int j = 0; j < 4; ++j) {
      int s = k * 1024 + t * 4 + j;
      uint32_t bits = tf_xor(nk0, nk1, 0u, nbase + (uint32_t)s);
      // u in (lo, 1): f*2.0 is exact, so bit-identical to XLA's f*(1-lo)+lo
      float u = fmaf(unit_f(bits), 2.0f, -0.99999994f);
      float nrm = 1.41421356f * erfinv_f(u);           // sqrt(2)*erfinv
      tmp[j] = (vals[k * 4 + j] + nrm * nscale) * msc;
    }
    float4 r; r.x = tmp[0]; r.y = tmp[1]; r.z = tmp[2]; r.w = tmp[3];
    ((float4*)orow)[k * 256 + t] = r;
  }
}

extern "C" void kernel_launch(void* const* d_in, const int* in_sizes, int n_in,
                              void* d_out, int out_size, void* d_ws, size_t ws_size,
                              hipStream_t stream) {
  const float* x = (const float*)d_in[0];
  float* out = (float*)d_out;
  int* shifts      = (int*)d_ws;
  float* scalev    = (float*)d_ws + 256;
  float* maskv     = (float*)d_ws + 512;
  uint32_t* nkeyp  = (uint32_t*)d_ws + 16896;

  k_params<<<2, 256, 0, stream>>>(shifts, scalev, maskv, nkeyp);
  k_main<<<16384, 256, 0, stream>>>(x, out, shifts, scalev, maskv, nkeyp);
}

// Round 2
// 414.362 us; speedup vs baseline: 1.0137x; 1.0137x over previous
//
#include <hip/hip_runtime.h>
#include <stdint.h>

#define SLEN 4096
#define NROWS 8192          // 128 * 64
#define VIEW_ELEMS 33554432 // 128 * 64 * 4096

// ---------------- threefry2x32 (JAX-exact, 20 rounds) ----------------
// rotl via v_alignbit_b32: ((x:x) >> (32-r)) == rotl(x, r)  — 1 VALU instr
#define ROTL(x, r) __builtin_amdgcn_alignbit((x), (x), 32u - (r))

__device__ __forceinline__ void tf2x32(uint32_t k0, uint32_t k1,
                                       uint32_t x0, uint32_t x1,
                                       uint32_t* o0, uint32_t* o1) {
  uint32_t ks2 = k0 ^ k1 ^ 0x1BD11BDAu;
  x0 += k0; x1 += k1;
#define TFR(r) { x0 += x1; x1 = ROTL(x1, r); x1 ^= x0; }
  TFR(13) TFR(15) TFR(26) TFR(6)
  x0 += k1; x1 += ks2 + 1u;
  TFR(17) TFR(29) TFR(16) TFR(24)
  x0 += ks2; x1 += k0 + 2u;
  TFR(13) TFR(15) TFR(26) TFR(6)
  x0 += k0; x1 += k1 + 3u;
  TFR(17) TFR(29) TFR(16) TFR(24)
  x0 += k1; x1 += ks2 + 4u;
  TFR(13) TFR(15) TFR(26) TFR(6)
#undef TFR
  *o0 = x0 + ks2;
  *o1 = x1 + k0 + 5u;
}

// partitionable random_bits, 32-bit: xor of the two output words
__device__ __forceinline__ uint32_t tf_xor(uint32_t k0, uint32_t k1,
                                           uint32_t x0, uint32_t x1) {
  uint32_t a, b;
  tf2x32(k0, k1, x0, x1, &a, &b);
  return a ^ b;
}

// uniform [0,1): top 23 bits as mantissa of [1,2) minus 1  (bit-exact vs JAX)
__device__ __forceinline__ float unit_f(uint32_t bits) {
  return __uint_as_float((bits >> 9) | 0x3F800000u) - 1.0f;
}

// XLA ErfInv32 (Giles) central polynomial; tail branch kept divergent (rare: ~0.34%)
__device__ __forceinline__ float erfinv_f(float x) {
  float w = -__logf(fmaf(x, -x, 1.0f));   // ~ -log1p(-x*x)
  float p;
  if (__builtin_expect(w >= 5.0f, 0)) {
    w = __fsqrt_rn(w) - 3.0f;
    p = -0.000200214257f;
    p = fmaf(p, w, 0.000100950558f);
    p = fmaf(p, w, 0.00134934322f);
    p = fmaf(p, w, -0.00367342844f);
    p = fmaf(p, w, 0.00573950773f);
    p = fmaf(p, w, -0.0076224613f);
    p = fmaf(p, w, 0.00943887047f);
    p = fmaf(p, w, 1.00167406f);
    p = fmaf(p, w, 2.83297682f);
  } else {
    w -= 2.5f;
    p = 2.81022636e-08f;
    p = fmaf(p, w, 3.43273939e-07f);
    p = fmaf(p, w, -3.5233877e-06f);
    p = fmaf(p, w, -4.39150654e-06f);
    p = fmaf(p, w, 0.00021858087f);
    p = fmaf(p, w, -0.00125372503f);
    p = fmaf(p, w, -0.00417768164f);
    p = fmaf(p, w, 0.246640727f);
    p = fmaf(p, w, 1.50140941f);
  }
  return p * x;
}

// ---------------- params kernel: shifts, channel mask, scale, noise keys ----
// ws layout (4-byte units): [0,256) shifts[2][128] (int)
//                           [256,512) scale[2][128]
//                           [512,16896) mask[2][8192]
//                           [16896,16900) nkey[2][2] (uint32)
__global__ __launch_bounds__(256) void k_params(int* __restrict__ shifts,
                                                float* __restrict__ scalev,
                                                float* __restrict__ maskv,
                                                uint32_t* __restrict__ nkey) {
  int v = blockIdx.x;            // 0/1 -> fold_in data v+1
  int t = threadIdx.x;

  // key_v = fold_in(key(42), v+1) = threefry((0,42), (0, v+1))
  uint32_t kv0, kv1;
  tf2x32(0u, 42u, 0u, (uint32_t)(v + 1), &kv0, &kv1);

  // split(key_v, 4) fold-like: subkey_i = threefry(key_v, (0, i))
  uint32_t ks0, ks1, kn0, kn1, km0, km1, kc0, kc1;
  tf2x32(kv0, kv1, 0u, 0u, &ks0, &ks1);   // k_shift
  tf2x32(kv0, kv1, 0u, 1u, &kn0, &kn1);   // k_noise
  tf2x32(kv0, kv1, 0u, 2u, &km0, &km1);   // k_mask
  tf2x32(kv0, kv1, 0u, 3u, &kc0, &kc1);   // k_scale

  // randint's internal split of k_shift
  uint32_t h10, h11, h20, h21;
  tf2x32(ks0, ks1, 0u, 0u, &h10, &h11);   // k1 -> higher bits
  tf2x32(ks0, ks1, 0u, 1u, &h20, &h21);   // k2 -> lower bits

  if (t < 128) {
    // shift: span=101, multiplier=(2^16%101)^2%101 = 68
    uint32_t hb = tf_xor(h10, h11, 0u, (uint32_t)t);
    uint32_t lb = tf_xor(h20, h21, 0u, (uint32_t)t);
    uint32_t off = ((hb % 101u) * 68u + (lb % 101u)) % 101u;
    shifts[v * 128 + t] = -50 + (int)off;
    // per-sample amplitude scale: max(0.8, f*(1.2-0.8)+0.8)
    uint32_t sb = tf_xor(kc0, kc1, 0u, (uint32_t)t);
    scalev[v * 128 + t] = fmaxf(0.8f, unit_f(sb) * (1.2f - 0.8f) + 0.8f);
  }
  // channel dropout mask, 8192 values per view
  for (int j = t; j < 8192; j += 256) {
    uint32_t mb = tf_xor(km0, km1, 0u, (uint32_t)j);
    maskv[v * 8192 + j] = (unit_f(mb) > 0.1f) ? 1.0f : 0.0f;
  }
  if (t == 0) { nkey[v * 2] = kn0; nkey[v * 2 + 1] = kn1; }
}

// ---------------- main kernel: one (view,b,c) row of 4096 per block --------
__global__ __launch_bounds__(256) void k_main(const float* __restrict__ x,
                                              float* __restrict__ out,
                                              const int* __restrict__ shifts,
                                              const float* __restrict__ scalev,
                                              const float* __restrict__ maskv,
                                              const uint32_t* __restrict__ nkey) {
  __shared__ float rowbuf[SLEN];   // 16 KB: the contiguous row, rolled on read
  __shared__ float red2[8];
  int blk = blockIdx.x;          // 16384 blocks = 2 views * 8192 rows
  int v = blk >> 13;
  int row = blk & 8191;          // b*64 + c
  int b = row >> 6;
  int t = threadIdx.x;

  float* orow = out + (size_t)v * VIEW_ELEMS + (size_t)row * SLEN;
  float4* orow4 = (float4*)orow;

  float mk = maskv[v * 8192 + row];
  if (mk == 0.0f) {
    // masked channel: output is exactly 0 — skip loads, std, threefry, erfinv
    float4 z; z.x = 0.0f; z.y = 0.0f; z.z = 0.0f; z.w = 0.0f;
#pragma unroll
    for (int k = 0; k < 4; ++k) orow4[k * 256 + t] = z;
    return;
  }

  int sh = shifts[v * 128 + b];
  float msc = mk * scalev[v * 128 + b];
  uint32_t nk0 = nkey[v * 2], nk1 = nkey[v * 2 + 1];

  const float4* __restrict__ xr4 = (const float4*)(x + (size_t)row * SLEN);

  // pass 1: contiguous float4 loads; sum/ss are permutation-invariant,
  // so no roll needed here. Stash row in LDS for the rolled pass-2 reads.
  float sum = 0.0f, ss = 0.0f;
#pragma unroll
  for (int k = 0; k < 4; ++k) {
    float4 a = xr4[k * 256 + t];
    sum += a.x + a.y + a.z + a.w;
    ss = fmaf(a.x, a.x, ss);
    ss = fmaf(a.y, a.y, ss);
    ss = fmaf(a.z, a.z, ss);
    ss = fmaf(a.w, a.w, ss);
    ((float4*)rowbuf)[k * 256 + t] = a;
  }
  // block reduction (sum, ss): wave butterfly then 4-partial LDS combine
#pragma unroll
  for (int o = 32; o > 0; o >>= 1) {
    sum += __shfl_xor(sum, o, 64);
    ss  += __shfl_xor(ss,  o, 64);
  }
  if ((t & 63) == 0) { red2[t >> 6] = sum; red2[4 + (t >> 6)] = ss; }
  __syncthreads();   // covers rowbuf writes AND red2 partials
  sum = red2[0] + red2[1] + red2[2] + red2[3];
  ss  = red2[4] + red2[5] + red2[6] + red2[7];
  float mean = sum * (1.0f / 4096.0f);
  float var = (ss - sum * mean) * (1.0f / 4095.0f);   // ddof=1
  float nscale = 0.1f * __fsqrt_rn(fmaxf(var, 0.0f)); // NOISE_STD * std
  float nsc2 = nscale * 1.41421356f * msc;            // fold sqrt(2) and mask*scale

  // pass 2: per-element threefry (partitionable layout), roll via LDS, store
  uint32_t nbase = (uint32_t)row * 4096u;
#pragma unroll
  for (int k = 0; k < 4; ++k) {
    float tmp[4];
#pragma unroll
    for (int j = 0; j < 4; ++j) {
      int s = k * 1024 + t * 4 + j;
      float val = rowbuf[(s - sh) & 4095];            // the circular roll
      uint32_t bits = tf_xor(nk0, nk1, 0u, nbase + (uint32_t)s);
      // u in (lo, 1): f*2.0 is exact, so bit-identical to XLA's f*(1-lo)+lo
      float u = fmaf(unit_f(bits), 2.0f, -0.99999994f);
      float nrm0 = erfinv_f(u);                       // sqrt(2) folded into nsc2
      tmp[j] = fmaf(nrm0, nsc2, val * msc);
    }
    float4 r; r.x = tmp[0]; r.y = tmp[1]; r.z = tmp[2]; r.w = tmp[3];
    orow4[k * 256 + t] = r;
  }
}

extern "C" void kernel_launch(void* const* d_in, const int* in_sizes, int n_in,
                              void* d_out, int out_size, void* d_ws, size_t ws_size,
                              hipStream_t stream) {
  const float* x = (const float*)d_in[0];
  float* out = (float*)d_out;
  int* shifts      = (int*)d_ws;
  float* scalev    = (float*)d_ws + 256;
  float* maskv     = (float*)d_ws + 512;
  uint32_t* nkeyp  = (uint32_t*)d_ws + 16896;

  k_params<<<2, 256, 0, stream>>>(shifts, scalev, maskv, nkeyp);
  k_main<<<16384, 256, 0, stream>>>(x, out, shifts, scalev, maskv, nkeyp);
}